// Round 13
// baseline (353.495 us; speedup 1.0000x reference)
//
#include <hip/hip_runtime.h>
#include <hip/hip_fp16.h>
#include <hip/hip_cooperative_groups.h>

namespace cg = cooperative_groups;

typedef _Float16 half8 __attribute__((ext_vector_type(8)));
typedef float float4v __attribute__((ext_vector_type(4)));

#define CHUNK 2048           // edges per scatter chunk
#define BS    128            // nodes per bucket
#define ARENA 6144           // arena capacity per bucket (mean cnt ~2046)
#define BCAP  6144           // LDS staging capacity in bucket phase
#define MGRID 256            // cooperative grid (1 block/CU)

__global__ void __launch_bounds__(1024, 4) k_mega(
        const float* __restrict__ x,
        const int* __restrict__ srcp, const int* __restrict__ dstp, int E, int N,
        const float* __restrict__ W1, const float* __restrict__ b1,
        const float* __restrict__ W2, const float* __restrict__ b2,
        const float* __restrict__ W3, const float* __restrict__ fcW,
        const float* __restrict__ b3, const float* __restrict__ fcb,
        int* __restrict__ gcur, int* __restrict__ spillCnt,
        double* __restrict__ pool, unsigned* __restrict__ spill,
        unsigned* __restrict__ pairs, unsigned short* __restrict__ col,
        int* __restrict__ rowbeg, int* __restrict__ degv,
        float* __restrict__ dinv, float* __restrict__ wfc,
        float* __restrict__ tvec, __half* __restrict__ gx,
        __half* __restrict__ g1, float* __restrict__ out) {
    cg::grid_group grid = cg::this_grid();
    const int t = threadIdx.x, bid = blockIdx.x, nblk = gridDim.x;

    __shared__ int lh[512], gstart[512];
    __shared__ unsigned pl[BCAP];
    __shared__ unsigned short scol[BCAP];
    __shared__ int hh[BS], nb[BS], cur[BS];
    __shared__ float sdi[BS];
    __shared__ float sW[640], sB[64];
    __shared__ __align__(16) __half At[4][16 * 72];
    __shared__ float sRed[4][4][16];
    __shared__ float sDi[4][16];
    __shared__ double sFin[256];

    const int NB = (E + CHUNK - 1) / CHUNK;
    const int K  = (N + BS - 1) >> 7;
    const int VB = (N + 15) >> 4;          // 16-node virtual blocks
    const int vq = t >> 8, tq = t & 255;   // 4 virtual 256-thr blocks per real block

    // ===== phase 0: init (block 0) =====
    if (bid == 0) {
        if (t < 512) gcur[t] = 0;
        if (t == 0) spillCnt[0] = 0;
        if (t >= 512 && t < 768) pool[t - 512] = 0.0;
        if (t < 64) {                      // wfc[c]=(W3@fcW)[c]; wfc[64]=b3.fcW
            float v = 0.f;
            #pragma unroll 8
            for (int j = 0; j < 64; ++j) v += W3[t * 64 + j] * fcW[j];
            wfc[t] = v;
            float bb = b3[t] * fcW[t];
            for (int o = 32; o > 0; o >>= 1) bb += __shfl_down(bb, o, 64);
            if (t == 0) wfc[64] = bb;
        }
    }
    grid.sync();

    // ===== phase A: scatter edges into bucket arenas =====
    for (int b = bid; b < NB; b += nblk) {
        if (t < 512) lh[t] = 0;
        __syncthreads();
        int e0 = b * CHUNK + t, e1 = e0 + 1024;
        bool v0 = e0 < E, v1 = e1 < E;
        int d0 = 0, s0 = 0, d1 = 0, s1 = 0;
        if (v0) { d0 = dstp[e0]; s0 = srcp[e0]; atomicAdd(&lh[d0 >> 7], 1); }
        if (v1) { d1 = dstp[e1]; s1 = srcp[e1]; atomicAdd(&lh[d1 >> 7], 1); }
        __syncthreads();
        if (t < 512) {
            int c = lh[t];
            gstart[t] = c ? atomicAdd(&gcur[t], c) : 0;
        }
        __syncthreads();
        if (t < 512) lh[t] = 0;
        __syncthreads();
        if (v0) {
            int k = d0 >> 7;
            int pos = gstart[k] + atomicAdd(&lh[k], 1);
            unsigned pk = ((unsigned)(d0 & 127) << 16) | (unsigned)s0;
            if (pos < ARENA) pairs[k * ARENA + pos] = pk;
            else { int sp = atomicAdd(spillCnt, 1); spill[sp] = ((unsigned)k << 23) | pk; }
        }
        if (v1) {
            int k = d1 >> 7;
            int pos = gstart[k] + atomicAdd(&lh[k], 1);
            unsigned pk = ((unsigned)(d1 & 127) << 16) | (unsigned)s1;
            if (pos < ARENA) pairs[k * ARENA + pos] = pk;
            else { int sp = atomicAdd(spillCnt, 1); spill[sp] = ((unsigned)k << 23) | pk; }
        }
        __syncthreads();
    }
    grid.sync();

    // ===== phase B: per-bucket CSR + rowbeg/deg/dinv/gx =====
    for (int k = bid; k < K; k += nblk) {
        int base = k * ARENA;
        int cnt = gcur[k];
        int cntA = cnt < ARENA ? cnt : ARENA;
        int spN = spillCnt[0];
        bool stg = cntA <= BCAP;
        if (t < BS) hh[t] = 0;
        if (stg) for (int i = t; i < cntA; i += 1024) pl[i] = pairs[base + i];
        __syncthreads();
        for (int i = t; i < cntA; i += 1024) {
            unsigned p = stg ? pl[i] : pairs[base + i];
            atomicAdd(&hh[p >> 16], 1);
        }
        for (int i = t; i < spN; i += 1024) {
            unsigned sp = spill[i];
            if ((int)(sp >> 23) == k) atomicAdd(&hh[(sp >> 16) & 127], 1);
        }
        __syncthreads();
        if (t < 64) {                      // wave-0 shuffle scan of hh -> nb
            int v0 = hh[2 * t], v1 = hh[2 * t + 1];
            int s = v0 + v1;
            #pragma unroll
            for (int o = 1; o < 64; o <<= 1) {
                int u = __shfl_up(s, o, 64);
                if (t >= o) s += u;
            }
            int excl = s - (v0 + v1);
            nb[2 * t] = excl + v0;
            nb[2 * t + 1] = excl + v0 + v1;
        }
        __syncthreads();
        if (t < BS) {
            int d = hh[t];
            int excl = nb[t] - d;
            cur[t] = excl;
            int gid = (k << 7) + t;
            if (gid < N) {
                rowbeg[gid] = base + excl;
                degv[gid] = d;
                float di = rsqrtf((float)(d + 1));
                dinv[gid] = di;
                sdi[t] = di;
            }
        }
        __syncthreads();
        for (int i = t; i < BS * 16; i += 1024) {
            int nl = i >> 4, q2 = i & 15;
            int gid = (k << 7) + nl;
            if (gid < N)
                gx[(unsigned)gid * 16 + q2] =
                    __float2half(q2 < 10 ? x[gid * 10 + q2] * sdi[nl] : 0.f);
        }
        for (int i = t; i < cntA; i += 1024) {
            unsigned p = stg ? pl[i] : pairs[base + i];
            int j = p >> 16;
            int pos = atomicAdd(&cur[j], 1);
            if (stg) scol[pos] = (unsigned short)(p & 0xFFFFu);
            else if (pos < ARENA) col[base + pos] = (unsigned short)(p & 0xFFFFu);
        }
        for (int i = t; i < spN; i += 1024) {
            unsigned sp = spill[i];
            if ((int)(sp >> 23) == k) {
                int j = (sp >> 16) & 127;
                int pos = atomicAdd(&cur[j], 1);
                if (stg && pos < BCAP) scol[pos] = (unsigned short)(sp & 0xFFFFu);
                else if (pos < ARENA) col[base + pos] = (unsigned short)(sp & 0xFFFFu);
            }
        }
        __syncthreads();
        if (stg) {
            int tot = cnt < BCAP ? cnt : BCAP;
            for (int i = t; i < tot; i += 1024) col[base + i] = scol[i];
        }
        __syncthreads();
    }
    grid.sync();

    // ===== phase C: layer 1 (4 virtual 256-thr blocks, 16 nodes each) =====
    for (int i = t; i < 640; i += 1024) sW[i] = W1[i];
    if (t < 64) sB[t] = b1[t];
    __syncthreads();
    for (int vb = bid * 4 + vq; vb < VB; vb += nblk * 4) {
        int node = vb * 16 + (tq >> 4);
        int f = tq & 15;
        bool live = node < N;
        bool act = live && (f < 10);
        const char* gp = (const char*)gx;
        unsigned fo = (unsigned)(f << 1);
        float di = live ? dinv[node] : 0.f;
        float a = act ? __half2float(*(const __half*)(gp + ((unsigned)node << 5) + fo)) : 0.f;
        int s0 = 0, s1 = 0;
        if (live) { s0 = rowbeg[node]; s1 = s0 + degv[node]; }
        int e = s0;
        for (; e + 4 <= s1; e += 4) {
            unsigned j0 = col[e], j1 = col[e + 1], j2 = col[e + 2], j3 = col[e + 3];
            float v0 = 0.f, v1 = 0.f, v2 = 0.f, v3 = 0.f;
            if (act) {
                v0 = __half2float(*(const __half*)(gp + (j0 << 5) + fo));
                v1 = __half2float(*(const __half*)(gp + (j1 << 5) + fo));
                v2 = __half2float(*(const __half*)(gp + (j2 << 5) + fo));
                v3 = __half2float(*(const __half*)(gp + (j3 << 5) + fo));
            }
            a += (v0 + v1) + (v2 + v3);
        }
        for (; e < s1; ++e) {
            unsigned j = col[e];
            if (act) a += __half2float(*(const __half*)(gp + (j << 5) + fo));
        }
        a *= di;
        int gb = tq & 48;
        float c0 = 0.f, c1 = 0.f, c2 = 0.f, c3 = 0.f;
        int c4 = 4 * f;
        #pragma unroll
        for (int kk = 0; kk < 10; ++kk) {
            float ak = __shfl(a, gb + kk, 64);
            c0 += ak * sW[kk * 64 + c4];
            c1 += ak * sW[kk * 64 + c4 + 1];
            c2 += ak * sW[kk * 64 + c4 + 2];
            c3 += ak * sW[kk * 64 + c4 + 3];
        }
        if (live) {
            float h0 = di * fmaxf(c0 + sB[c4], 0.f);
            float h1 = di * fmaxf(c1 + sB[c4 + 1], 0.f);
            float h2 = di * fmaxf(c2 + sB[c4 + 2], 0.f);
            float h3 = di * fmaxf(c3 + sB[c4 + 3], 0.f);
            union { __half h[4]; uint2 u; } pk;
            pk.h[0] = __float2half(h0); pk.h[1] = __float2half(h1);
            pk.h[2] = __float2half(h2); pk.h[3] = __float2half(h3);
            *(uint2*)((char*)g1 + ((unsigned)node << 7) + (unsigned)(f << 3)) = pk.u;
        }
    }
    grid.sync();

    // ===== phase D: layer 2 (gather g1 + MFMA -> tvec) =====
    {
        int lane = tq & 63, wid = tq >> 6;
        int m = lane & 15, quad = lane >> 4;
        int cgi = (wid << 4) + m;
        half8 H0, L0, H1, L1;
        #pragma unroll
        for (int j = 0; j < 8; ++j) {
            float w0 = W2[(quad * 8 + j) * 64 + cgi];
            _Float16 h0 = (_Float16)w0;
            H0[j] = h0; L0[j] = (_Float16)(w0 - (float)h0);
            float w1 = W2[(32 + quad * 8 + j) * 64 + cgi];
            _Float16 h1 = (_Float16)w1;
            H1[j] = h1; L1[j] = (_Float16)(w1 - (float)h1);
        }
        float bc = b2[cgi], wf = wfc[cgi];
        int nl = tq >> 4, f4 = tq & 15;
        int nIter = (VB + nblk * 4 - 1) / (nblk * 4);
        for (int it = 0; it < nIter; ++it) {
            int vb = (it * nblk + bid) * 4 + vq;
            bool vbOK = vb < VB;
            int node = vb * 16 + nl;
            bool live = vbOK && node < N;
            float di = live ? dinv[node] : 0.f;
            float ax = 0.f, ay = 0.f, az = 0.f, aw = 0.f;
            if (live) {
                const char* gp = (const char*)g1;
                unsigned fo = (unsigned)(f4 << 3);
                uint2 us = *(const uint2*)(gp + ((unsigned)node << 7) + fo);
                float2 slo = __half22float2(*(__half2*)&us.x);
                float2 shi = __half22float2(*(__half2*)&us.y);
                ax = slo.x; ay = slo.y; az = shi.x; aw = shi.y;
                int s0 = rowbeg[node], s1 = s0 + degv[node];
                int e = s0;
                for (; e + 8 <= s1; e += 8) {
                    unsigned j0 = col[e],     j1 = col[e + 1], j2 = col[e + 2], j3 = col[e + 3];
                    unsigned j4 = col[e + 4], j5 = col[e + 5], j6 = col[e + 6], j7 = col[e + 7];
                    uint2 u0 = *(const uint2*)(gp + (j0 << 7) + fo);
                    uint2 u1 = *(const uint2*)(gp + (j1 << 7) + fo);
                    uint2 u2 = *(const uint2*)(gp + (j2 << 7) + fo);
                    uint2 u3 = *(const uint2*)(gp + (j3 << 7) + fo);
                    uint2 u4 = *(const uint2*)(gp + (j4 << 7) + fo);
                    uint2 u5 = *(const uint2*)(gp + (j5 << 7) + fo);
                    uint2 u6 = *(const uint2*)(gp + (j6 << 7) + fo);
                    uint2 u7 = *(const uint2*)(gp + (j7 << 7) + fo);
                    float2 a0 = __half22float2(*(__half2*)&u0.x), b0 = __half22float2(*(__half2*)&u0.y);
                    float2 a1 = __half22float2(*(__half2*)&u1.x), b1v = __half22float2(*(__half2*)&u1.y);
                    float2 a2 = __half22float2(*(__half2*)&u2.x), b2v = __half22float2(*(__half2*)&u2.y);
                    float2 a3 = __half22float2(*(__half2*)&u3.x), b3v = __half22float2(*(__half2*)&u3.y);
                    float2 a4 = __half22float2(*(__half2*)&u4.x), b4 = __half22float2(*(__half2*)&u4.y);
                    float2 a5 = __half22float2(*(__half2*)&u5.x), b5 = __half22float2(*(__half2*)&u5.y);
                    float2 a6 = __half22float2(*(__half2*)&u6.x), b6 = __half22float2(*(__half2*)&u6.y);
                    float2 a7 = __half22float2(*(__half2*)&u7.x), b7 = __half22float2(*(__half2*)&u7.y);
                    ax += ((a0.x + a1.x) + (a2.x + a3.x)) + ((a4.x + a5.x) + (a6.x + a7.x));
                    ay += ((a0.y + a1.y) + (a2.y + a3.y)) + ((a4.y + a5.y) + (a6.y + a7.y));
                    az += ((b0.x + b1v.x) + (b2v.x + b3v.x)) + ((b4.x + b5.x) + (b6.x + b7.x));
                    aw += ((b0.y + b1v.y) + (b2v.y + b3v.y)) + ((b4.y + b5.y) + (b6.y + b7.y));
                }
                for (; e < s1; ++e) {
                    uint2 u0 = *(const uint2*)(gp + ((unsigned)col[e] << 7) + fo);
                    float2 a0 = __half22float2(*(__half2*)&u0.x), b0 = __half22float2(*(__half2*)&u0.y);
                    ax += a0.x; ay += a0.y; az += b0.x; aw += b0.y;
                }
            }
            union { __half h[4]; uint2 u; } pk;
            pk.h[0] = __float2half(ax * di); pk.h[1] = __float2half(ay * di);
            pk.h[2] = __float2half(az * di); pk.h[3] = __float2half(aw * di);
            if (vbOK) {
                *(uint2*)&At[vq][nl * 72 + 4 * f4] = pk.u;
                if (f4 == 0) sDi[vq][nl] = di;
            }
            __syncthreads();
            half8 A0 = *reinterpret_cast<const half8*>(&At[vq][m * 72 + quad * 8]);
            half8 A1 = *reinterpret_cast<const half8*>(&At[vq][m * 72 + 32 + quad * 8]);
            float4v C = {0.f, 0.f, 0.f, 0.f};
            C = __builtin_amdgcn_mfma_f32_16x16x32_f16(A0, H0, C, 0, 0, 0);
            C = __builtin_amdgcn_mfma_f32_16x16x32_f16(A0, L0, C, 0, 0, 0);
            C = __builtin_amdgcn_mfma_f32_16x16x32_f16(A1, H1, C, 0, 0, 0);
            C = __builtin_amdgcn_mfma_f32_16x16x32_f16(A1, L1, C, 0, 0, 0);
            float v0 = fmaxf(C[0] + bc, 0.f) * wf;
            float v1 = fmaxf(C[1] + bc, 0.f) * wf;
            float v2 = fmaxf(C[2] + bc, 0.f) * wf;
            float v3 = fmaxf(C[3] + bc, 0.f) * wf;
            #pragma unroll
            for (int o = 1; o < 16; o <<= 1) {
                v0 += __shfl_xor(v0, o, 64);
                v1 += __shfl_xor(v1, o, 64);
                v2 += __shfl_xor(v2, o, 64);
                v3 += __shfl_xor(v3, o, 64);
            }
            if (m == 0 && vbOK) {
                sRed[vq][wid][quad * 4 + 0] = v0;
                sRed[vq][wid][quad * 4 + 1] = v1;
                sRed[vq][wid][quad * 4 + 2] = v2;
                sRed[vq][wid][quad * 4 + 3] = v3;
            }
            __syncthreads();
            if (tq < 16 && vbOK) {
                int ng = vb * 16 + tq;
                if (ng < N) {
                    float tt = sRed[vq][0][tq] + sRed[vq][1][tq] + sRed[vq][2][tq] + sRed[vq][3][tq];
                    tvec[ng] = sDi[vq][tq] * tt;
                }
            }
            __syncthreads();
        }
    }
    grid.sync();

    // ===== phase E: layer 3 gather + mean-pool =====
    {
        long long total = (long long)N * 16;
        for (long long idx = (long long)bid * 1024 + t; idx < total; idx += (long long)nblk * 1024) {
            int node = (int)(idx >> 4), lane = (int)(idx & 15);
            int s0 = rowbeg[node], s1 = s0 + degv[node];
            float s = 0.f;
            for (int e = s0 + lane; e < s1; e += 16) s += tvec[col[e]];
            #pragma unroll
            for (int o = 1; o < 16; o <<= 1) s += __shfl_xor(s, o, 64);
            if (lane == 0) {
                double contrib = (double)(dinv[node] * (tvec[node] + s));
                atomicAdd(&pool[node & 255], contrib);
            }
        }
    }
    grid.sync();

    // ===== phase F: final reduce (block 0) =====
    if (bid == 0) {
        if (t < 256) sFin[t] = pool[t];
        __syncthreads();
        for (int o = 128; o > 0; o >>= 1) {
            if (t < o && t < 256) sFin[t] += sFin[t + o];
            __syncthreads();
        }
        if (t == 0) out[0] = (float)(sFin[0] * (1.0 / (double)N)) + wfc[64] + fcb[0];
    }
}

extern "C" void kernel_launch(void* const* d_in, const int* in_sizes, int n_in,
                              void* d_out, int out_size, void* d_ws, size_t ws_size,
                              hipStream_t stream) {
    const float* x   = (const float*)d_in[0];
    const int*   ei  = (const int*)d_in[1];
    const float* W1  = (const float*)d_in[2];
    const float* b1  = (const float*)d_in[3];
    const float* W2  = (const float*)d_in[4];
    const float* b2  = (const float*)d_in[5];
    const float* W3  = (const float*)d_in[6];
    const float* b3  = (const float*)d_in[7];
    const float* fcW = (const float*)d_in[8];
    const float* fcb = (const float*)d_in[9];

    int N = in_sizes[0] / 10;
    int E = in_sizes[1] / 2;
    const int* src = ei;
    const int* dst = ei + E;

    const int K = (N + BS - 1) >> 7;

    // ---- workspace carve-up (256B aligned) ----
    char* w = (char*)d_ws;
    size_t off = 0;
    auto alloc = [&](size_t bytes) -> void* {
        void* p = w + off;
        off += (bytes + 255) & ~(size_t)255;
        return p;
    };
    int*      gcur       = (int*)alloc(512 * 4);
    int*      spillCnt   = (int*)alloc(256);
    double*   pool       = (double*)alloc(256 * 8);
    unsigned* spill      = (unsigned*)alloc((size_t)E * 4);
    unsigned* pairs      = (unsigned*)alloc((size_t)K * ARENA * 4);
    unsigned short* col  = (unsigned short*)alloc((size_t)K * ARENA * 2);
    int*      rowbeg     = (int*)alloc((size_t)N * 4);
    int*      degv       = (int*)alloc((size_t)N * 4);
    float*    dinv       = (float*)alloc((size_t)N * 4);
    float*    wfc        = (float*)alloc(65 * 4);
    float*    tvec       = (float*)alloc((size_t)N * 4);
    __half*   gx         = (__half*)alloc((size_t)N * 16 * 2);
    __half*   g1         = (__half*)alloc((size_t)N * 64 * 2);
    (void)ws_size; (void)n_in; (void)out_size;

    float* outp = (float*)d_out;
    void* args[] = {
        (void*)&x, (void*)&src, (void*)&dst, (void*)&E, (void*)&N,
        (void*)&W1, (void*)&b1, (void*)&W2, (void*)&b2,
        (void*)&W3, (void*)&fcW, (void*)&b3, (void*)&fcb,
        (void*)&gcur, (void*)&spillCnt, (void*)&pool, (void*)&spill,
        (void*)&pairs, (void*)&col, (void*)&rowbeg, (void*)&degv,
        (void*)&dinv, (void*)&wfc, (void*)&tvec, (void*)&gx,
        (void*)&g1, (void*)&outp
    };
    hipLaunchCooperativeKernel((void*)k_mega, dim3(MGRID), dim3(1024),
                               args, 0, stream);
}